// Round 6
// baseline (1492.924 us; speedup 1.0000x reference)
//
#include <hip/hip_runtime.h>

typedef float f32x4 __attribute__((ext_vector_type(4)));
typedef _Float16 f16x8 __attribute__((ext_vector_type(8)));
typedef int i32x4 __attribute__((ext_vector_type(4)));

__device__ __forceinline__ unsigned short f2h_bits(float f) {
    _Float16 h = (_Float16)f;
    return __builtin_bit_cast(unsigned short, h);
}
__device__ __forceinline__ float sigmoidf(float x) { return 1.0f / (1.0f + expf(-x)); }

// ---------------------------------------------------------------------------
// Setup A (33 blocks x 256) — UNCHANGED verified kernel.
// ---------------------------------------------------------------------------
__global__ void fractal_setup_a(const float* __restrict__ csl, const float* __restrict__ cls,
                                const float* __restrict__ sp, const float* __restrict__ sdl,
                                float* __restrict__ smg, float* __restrict__ csmg,
                                float* __restrict__ tbl) {
    const int tid = threadIdx.x;
    if (blockIdx.x < 32) {
        const int w = tid >> 6;
        const int lane = tid & 63;
        const int r = blockIdx.x * 4 + w;          // 0..127
        const int node = r & 63;
        const int side = r >> 6;
        const float v = csl[node * 128 + side * 64 + lane];
        float mx = v;
#pragma unroll
        for (int msk = 1; msk < 64; msk <<= 1) mx = fmaxf(mx, __shfl_xor(mx, msk, 64));
        const float e = expf(v - mx);
        float sum = e;
#pragma unroll
        for (int msk = 1; msk < 64; msk <<= 1) sum += __shfl_xor(sum, msk, 64);
        smg[r * 64 + lane] = e / sum;
    } else {
        if (tid < 64) {
            const float* rowp = cls + tid * 16;
            float mx = -1e30f;
            for (int j = 0; j < 16; ++j) mx = fmaxf(mx, rowp[j]);
            float ssum = 0.f;
            for (int j = 0; j < 16; ++j) ssum += expf(rowp[j] - mx);
            const float inv = 1.0f / ssum;
            for (int j = 0; j < 16; ++j) csmg[tid * 16 + j] = expf(rowp[j] - mx) * inv;
        } else if (tid >= 128 && tid < 192) {
            tbl[tid - 128] = expf(-sp[tid - 128]);
        } else if (tid >= 192) {
            tbl[64 + tid - 192] = sigmoidf(sdl[tid - 192]);
        }
    }
}

// ---------------------------------------------------------------------------
// Setup B (45 blocks x 256) — UNCHANGED verified kernel (R1).
// ---------------------------------------------------------------------------
__global__ void fractal_setup_b(const float* __restrict__ smg, const float* __restrict__ csmg,
                                unsigned short* __restrict__ frag_out,
                                float* __restrict__ row0) {
    const int e = blockIdx.x * 256 + threadIdx.x;
    if (e < 8192) {
        const int j = e & 7;
        const int l = (e >> 3) & 63;
        const int fi = e >> 9;
        const int t = fi >> 2, c = fi & 3;
        const int i = l & 15;
        const int n = 8 * (i >> 2) + (i & 3) + 4 * (t & 1) + 32 * (t >> 1);  // tau(t,i)
        const int k0 = (c & 1) * 32 + (l >> 4) * 8 + j;   // node index 0..63
        float v;
        if (c < 2) v = smg[(64 + k0) * 64 + n];                         // R
        else       v = smg[k0 * 64 + n] - smg[(64 + k0) * 64 + n];      // L - R
        frag_out[e] = f2h_bits(v);
    } else if (e < 9216) {
        const int e2 = e - 8192;   // 0..1023  (plain Csm frags, kept for md==0/legacy)
        const int j = e2 & 7;
        const int l = (e2 >> 3) & 63;
        const int c = e2 >> 9;
        const int n = l & 15;
        const int k = c * 32 + (l >> 4) * 8 + j;
        frag_out[8192 + e2] = f2h_bits(csmg[k * 16 + n]);
    } else if (e < 11264) {
        // Fused final-step fragments: A[class, k] with
        //   f=0,1 -> RC[k, class], f=2,3 -> LmRC[k, class], k = (f&1)*32 + koff
        const int e3 = e - 9216;            // 0..2047
        const int f = e3 >> 9;              // 0..3
        const int rem = e3 & 511;
        const int j = rem & 7;
        const int l = (rem >> 3) & 63;
        const int cls = l & 15;
        const int k = (f & 1) * 32 + ((l >> 4) << 3) + j;   // node 0..63
        float acc = 0.f;
        if (f < 2) {
            for (int n = 0; n < 64; ++n)
                acc += smg[(64 + k) * 64 + n] * csmg[n * 16 + cls];
        } else {
            for (int n = 0; n < 64; ++n)
                acc += (smg[k * 64 + n] - smg[(64 + k) * 64 + n]) * csmg[n * 16 + cls];
        }
        frag_out[9216 + e3] = f2h_bits(acc);
    } else if (e < 11392) {
        const int e2 = e - 11264;           // 0..127
        // row0[k] = R[0,k]; row0[64+k] = L[0,k] - R[0,k]
        row0[e2] = (e2 < 64) ? smg[4096 + e2]
                             : (smg[e2 - 64] - smg[4096 + (e2 - 64)]);
    }
}

// One depth step for both chains (verified R11 body, factored for unrolling).
// (R5's setprio REVERTED: it perturbed regalloc 76->84 and cost 5%.)
__device__ __forceinline__ void fractal_step(const f16x8 (&bfr)[4][4],
                                             const f16x8& lfA0, const f16x8& lfA1,
                                             const f16x8& lfB0, const f16x8& lfB1,
                                             i32x4& puA0, i32x4& puA1,
                                             i32x4& puB0, i32x4& puB1) {
    const f16x8 pfA0 = __builtin_bit_cast(f16x8, puA0);
    const f16x8 pfA1 = __builtin_bit_cast(f16x8, puA1);
    const f16x8 pfB0 = __builtin_bit_cast(f16x8, puB0);
    const f16x8 pfB1 = __builtin_bit_cast(f16x8, puB1);
    const f16x8 aA0 = pfA0 * lfA0;   // v_pk_mul_f16
    const f16x8 aA1 = pfA1 * lfA1;
    const f16x8 aB0 = pfB0 * lfB0;
    const f16x8 aB1 = pfB1 * lfB1;
    int PA[4], QA[4], PB[4], QB[4];
#pragma unroll
    for (int t = 0; t < 4; ++t) {
        f32x4 CA = {0.f, 0.f, 0.f, 0.f};
        f32x4 CB = {0.f, 0.f, 0.f, 0.f};
        CA = __builtin_amdgcn_mfma_f32_16x16x32_f16(bfr[t][0], pfA0, CA, 0, 0, 0);
        CB = __builtin_amdgcn_mfma_f32_16x16x32_f16(bfr[t][0], pfB0, CB, 0, 0, 0);
        CA = __builtin_amdgcn_mfma_f32_16x16x32_f16(bfr[t][1], pfA1, CA, 0, 0, 0);
        CB = __builtin_amdgcn_mfma_f32_16x16x32_f16(bfr[t][1], pfB1, CB, 0, 0, 0);
        CA = __builtin_amdgcn_mfma_f32_16x16x32_f16(bfr[t][2], aA0, CA, 0, 0, 0);
        CB = __builtin_amdgcn_mfma_f32_16x16x32_f16(bfr[t][2], aB0, CB, 0, 0, 0);
        CA = __builtin_amdgcn_mfma_f32_16x16x32_f16(bfr[t][3], aA1, CA, 0, 0, 0);
        CB = __builtin_amdgcn_mfma_f32_16x16x32_f16(bfr[t][3], aB1, CB, 0, 0, 0);
        PA[t] = __builtin_bit_cast(int, __builtin_amdgcn_cvt_pkrtz(CA[0], CA[1]));
        QA[t] = __builtin_bit_cast(int, __builtin_amdgcn_cvt_pkrtz(CA[2], CA[3]));
        PB[t] = __builtin_bit_cast(int, __builtin_amdgcn_cvt_pkrtz(CB[0], CB[1]));
        QB[t] = __builtin_bit_cast(int, __builtin_amdgcn_cvt_pkrtz(CB[2], CB[3]));
    }
    // tau labeling: pure register renaming into next state
    puA0.x = PA[0]; puA0.y = QA[0]; puA0.z = PA[1]; puA0.w = QA[1];
    puA1.x = PA[2]; puA1.y = QA[2]; puA1.z = PA[3]; puA1.w = QA[3];
    puB0.x = PB[0]; puB0.y = QB[0]; puB0.z = PB[1]; puB0.w = QB[1];
    puB1.x = PB[2]; puB1.y = QB[2]; puB1.z = PB[3]; puB1.w = QB[3];
}

// ---------------------------------------------------------------------------
// Main: exact R1 body. ONLY change: __launch_bounds__(256, 2) -> (256, 6).
// Decisive A/B for the residency-governor theory: every non-spilled run
// ((256,2): R0/R1/R5) measures ~2.37-2.4 waves/SIMD = the declared min,
// while VGPR=76 (granule 80) permits 6 waves/SIMD. Raising the declared min
// to 6 keeps the allocator cap at 512/6~85 >= 76 (NO spill, codegen ~= R1 —
// unlike R3/R4 where cap 64 < demand forced the bfr spill) but raises the
// declared residency target to exactly the HW resource limit. If occupancy
// jumps -> mechanism confirmed + big win; if it stays 2.4 -> theory dead,
// pivot to setup-kernel fusion (66us of non-main time).
// ---------------------------------------------------------------------------
__global__ __launch_bounds__(256, 6)
void fractal_main(const float* __restrict__ x_pos, const float* __restrict__ y_pos,
                  const int* __restrict__ mdp,
                  const unsigned short* __restrict__ frags,
                  const float* __restrict__ tbl,
                  const float* __restrict__ row0,
                  const float* __restrict__ csmg,
                  float* __restrict__ out) {
    const int tid = threadIdx.x;
    const int w = tid >> 6;
    const int l = tid & 63;
    const int q = l >> 4;
    const int m = l & 15;
    const int rowbase = (blockIdx.x * 4 + w) * 32;   // 32 points per wave

    const int md = mdp[0];
    if (md == 0) {
        // p = e0 -> out = Csm[0,:] for every point (then normalize).
        const f32x4 cv = *(const f32x4*)(csmg + 4 * q);
        float s = cv[0] + cv[1] + cv[2] + cv[3];
        s += __shfl_xor(s, 16, 64);
        s += __shfl_xor(s, 32, 64);
        const float inv = 1.0f / fmaxf(s, 1e-10f);
        f32x4 res;
#pragma unroll
        for (int r = 0; r < 4; ++r) res[r] = cv[r] * inv;
        *(f32x4*)(out + (rowbase + m) * 16 + 4 * q) = res;
        *(f32x4*)(out + (rowbase + 16 + m) * 16 + 4 * q) = res;
        return;
    }

    // Resident fragments: [R; L-R] (64 VGPRs), shared by both chains
    const f16x8* __restrict__ fgp = (const f16x8*)frags;
    f16x8 bfr[4][4];
#pragma unroll
    for (int t = 0; t < 4; ++t)
#pragma unroll
        for (int c = 0; c < 4; ++c) bfr[t][c] = fgp[(t * 4 + c) * 64 + l];

    // Vectorized tbl loads
    f32x4 tE0[2], tE1[2], tD0[2], tD1[2];
    tE0[0] = *(const f32x4*)(tbl + 8 * q);       tE0[1] = *(const f32x4*)(tbl + 8 * q + 4);
    tE1[0] = *(const f32x4*)(tbl + 32 + 8 * q);  tE1[1] = *(const f32x4*)(tbl + 32 + 8 * q + 4);
    tD0[0] = *(const f32x4*)(tbl + 64 + 8 * q);  tD0[1] = *(const f32x4*)(tbl + 64 + 8 * q + 4);
    tD1[0] = *(const f32x4*)(tbl + 96 + 8 * q);  tD1[1] = *(const f32x4*)(tbl + 96 + 8 * q + 4);

    const float xA = x_pos[rowbase + m],      yA = y_pos[rowbase + m];
    const float xB = x_pos[rowbase + 16 + m], yB = y_pos[rowbase + 16 + m];
    const float exA = __expf(xA), eyA = __expf(yA);
    const float exB = __expf(xB), eyB = __expf(yB);

    f16x8 lfA0, lfA1, lfB0, lfB1;
#pragma unroll
    for (int j = 0; j < 8; ++j) {
        const float E0 = tE0[j >> 2][j & 3];
        const float E1 = tE1[j >> 2][j & 3];
        const float d0 = tD0[j >> 2][j & 3];
        const float d1 = tD1[j >> 2][j & 3];
        {
            const float h0 = __builtin_amdgcn_rcpf(__builtin_fmaf(exA, E0, 1.0f));
            const float v0 = __builtin_amdgcn_rcpf(__builtin_fmaf(eyA, E0, 1.0f));
            const float h1 = __builtin_amdgcn_rcpf(__builtin_fmaf(exA, E1, 1.0f));
            const float v1 = __builtin_amdgcn_rcpf(__builtin_fmaf(eyA, E1, 1.0f));
            lfA0[j] = (_Float16)(h0 + d0 * (v0 - h0));
            lfA1[j] = (_Float16)(h1 + d1 * (v1 - h1));
        }
        {
            const float h0 = __builtin_amdgcn_rcpf(__builtin_fmaf(exB, E0, 1.0f));
            const float v0 = __builtin_amdgcn_rcpf(__builtin_fmaf(eyB, E0, 1.0f));
            const float h1 = __builtin_amdgcn_rcpf(__builtin_fmaf(exB, E1, 1.0f));
            const float v1 = __builtin_amdgcn_rcpf(__builtin_fmaf(eyB, E1, 1.0f));
            lfB0[j] = (_Float16)(h0 + d0 * (v0 - h0));
            lfB1[j] = (_Float16)(h1 + d1 * (v1 - h1));
        }
    }

    i32x4 puA0, puA1, puB0, puB1;
    if (md >= 2) {
        // Direct step-1 init: p1[k] = R[0,k] + left[b,0]*(L-R)[0,k]
        const float E00 = tbl[0];    // exp(-sp[0])
        const float dir0 = tbl[64];  // sigmoid(sdl[0])
        float lA, lB;
        {
            const float h = __builtin_amdgcn_rcpf(__builtin_fmaf(exA, E00, 1.0f));
            const float v = __builtin_amdgcn_rcpf(__builtin_fmaf(eyA, E00, 1.0f));
            lA = h + dir0 * (v - h);
        }
        {
            const float h = __builtin_amdgcn_rcpf(__builtin_fmaf(exB, E00, 1.0f));
            const float v = __builtin_amdgcn_rcpf(__builtin_fmaf(eyB, E00, 1.0f));
            lB = h + dir0 * (v - h);
        }
        f32x4 rRa[2], rRb[2], rDa[2], rDb[2];
        rRa[0] = *(const f32x4*)(row0 + 8 * q);       rRa[1] = *(const f32x4*)(row0 + 8 * q + 4);
        rRb[0] = *(const f32x4*)(row0 + 32 + 8 * q);  rRb[1] = *(const f32x4*)(row0 + 32 + 8 * q + 4);
        rDa[0] = *(const f32x4*)(row0 + 64 + 8 * q);  rDa[1] = *(const f32x4*)(row0 + 64 + 8 * q + 4);
        rDb[0] = *(const f32x4*)(row0 + 96 + 8 * q);  rDb[1] = *(const f32x4*)(row0 + 96 + 8 * q + 4);
        f16x8 pA0, pA1, pB0, pB1;
#pragma unroll
        for (int j = 0; j < 8; ++j) {
            const float R0 = rRa[j >> 2][j & 3], R1 = rRb[j >> 2][j & 3];
            const float D0 = rDa[j >> 2][j & 3], D1 = rDb[j >> 2][j & 3];
            pA0[j] = (_Float16)__builtin_fmaf(lA, D0, R0);
            pA1[j] = (_Float16)__builtin_fmaf(lA, D1, R1);
            pB0[j] = (_Float16)__builtin_fmaf(lB, D0, R0);
            pB1[j] = (_Float16)__builtin_fmaf(lB, D1, R1);
        }
        puA0 = __builtin_bit_cast(i32x4, pA0);
        puA1 = __builtin_bit_cast(i32x4, pA1);
        puB0 = __builtin_bit_cast(i32x4, pB0);
        puB1 = __builtin_bit_cast(i32x4, pB1);

        if (md == 10) {
#pragma unroll
            for (int d = 0; d < 8; ++d)
                fractal_step(bfr, lfA0, lfA1, lfB0, lfB1, puA0, puA1, puB0, puB1);
        } else {
            for (int d = 0; d < md - 2; ++d)
                fractal_step(bfr, lfA0, lfA1, lfB0, lfB1, puA0, puA1, puB0, puB1);
        }
    } else {  // md == 1: p = e0, fused final does step 1 + projection
        puA0 = (i32x4){0, 0, 0, 0}; puA1 = (i32x4){0, 0, 0, 0};
        puB0 = (i32x4){0, 0, 0, 0}; puB1 = (i32x4){0, 0, 0, 0};
        if (q == 0) { puA0.x = 0x3C00; puB0.x = 0x3C00; }   // f16(1.0)
    }

    // Fused final step + class projection: out^T = [RC; LmRC]^T applied to
    // [p; p*left]. Load fused frags only now (not loop-live).
    f16x8 bfin[4];
#pragma unroll
    for (int f = 0; f < 4; ++f) bfin[f] = fgp[1152 + f * 64 + l];

    {
        const f16x8 pf0 = __builtin_bit_cast(f16x8, puA0);
        const f16x8 pf1 = __builtin_bit_cast(f16x8, puA1);
        const f16x8 a0 = pf0 * lfA0;
        const f16x8 a1 = pf1 * lfA1;
        f32x4 o = {0.f, 0.f, 0.f, 0.f};
        o = __builtin_amdgcn_mfma_f32_16x16x32_f16(bfin[0], pf0, o, 0, 0, 0);
        o = __builtin_amdgcn_mfma_f32_16x16x32_f16(bfin[1], pf1, o, 0, 0, 0);
        o = __builtin_amdgcn_mfma_f32_16x16x32_f16(bfin[2], a0, o, 0, 0, 0);
        o = __builtin_amdgcn_mfma_f32_16x16x32_f16(bfin[3], a1, o, 0, 0, 0);
        float s = o[0] + o[1] + o[2] + o[3];
        s += __shfl_xor(s, 16, 64);
        s += __shfl_xor(s, 32, 64);
        const float inv = 1.0f / fmaxf(s, 1e-10f);
        f32x4 res;
#pragma unroll
        for (int r = 0; r < 4; ++r) res[r] = o[r] * inv;
        *(f32x4*)(out + (rowbase + m) * 16 + 4 * q) = res;
    }
    {
        const f16x8 pf0 = __builtin_bit_cast(f16x8, puB0);
        const f16x8 pf1 = __builtin_bit_cast(f16x8, puB1);
        const f16x8 a0 = pf0 * lfB0;
        const f16x8 a1 = pf1 * lfB1;
        f32x4 o = {0.f, 0.f, 0.f, 0.f};
        o = __builtin_amdgcn_mfma_f32_16x16x32_f16(bfin[0], pf0, o, 0, 0, 0);
        o = __builtin_amdgcn_mfma_f32_16x16x32_f16(bfin[1], pf1, o, 0, 0, 0);
        o = __builtin_amdgcn_mfma_f32_16x16x32_f16(bfin[2], a0, o, 0, 0, 0);
        o = __builtin_amdgcn_mfma_f32_16x16x32_f16(bfin[3], a1, o, 0, 0, 0);
        float s = o[0] + o[1] + o[2] + o[3];
        s += __shfl_xor(s, 16, 64);
        s += __shfl_xor(s, 32, 64);
        const float inv = 1.0f / fmaxf(s, 1e-10f);
        f32x4 res;
#pragma unroll
        for (int r = 0; r < 4; ++r) res[r] = o[r] * inv;
        *(f32x4*)(out + (rowbase + 16 + m) * 16 + 4 * q) = res;
    }
}

extern "C" void kernel_launch(void* const* d_in, const int* in_sizes, int n_in,
                              void* d_out, int out_size, void* d_ws, size_t ws_size,
                              hipStream_t stream) {
    const float* x_pos = (const float*)d_in[0];
    const float* y_pos = (const float*)d_in[1];
    const float* sp    = (const float*)d_in[2];
    const float* sdl   = (const float*)d_in[3];
    const float* cls   = (const float*)d_in[4];
    const float* csl   = (const float*)d_in[5];
    const int*   mdp   = (const int*)d_in[6];

    // d_ws layout:
    //  [0,      22528) frags: 16 main + 2 csm + 4 fused = 11264 halves
    //  [22528,  23040) tbl   (128 f32)
    //  [23040,  23552) row0  (128 f32)
    //  [23552,  56320) smg   (128x64 f32)
    //  [56320,  60416) csmg  (64x16 f32)
    unsigned short* frags = (unsigned short*)d_ws;
    float* tbl  = (float*)((char*)d_ws + 22528);
    float* row0 = (float*)((char*)d_ws + 23040);
    float* smg  = (float*)((char*)d_ws + 23552);
    float* csmg = (float*)((char*)d_ws + 56320);

    fractal_setup_a<<<33, 256, 0, stream>>>(csl, cls, sp, sdl, smg, csmg, tbl);
    fractal_setup_b<<<45, 256, 0, stream>>>(smg, csmg, frags, row0);

    const int B = in_sizes[0];  // 1048576 points; 128 points per block
    fractal_main<<<B / 128, 256, 0, stream>>>(x_pos, y_pos, mdp, frags, tbl, row0,
                                              csmg, (float*)d_out);
}

// Round 7
// 221.812 us; speedup vs baseline: 6.7306x; 6.7306x over previous
//
#include <hip/hip_runtime.h>

typedef float f32x4 __attribute__((ext_vector_type(4)));
typedef _Float16 f16x8 __attribute__((ext_vector_type(8)));
typedef int i32x4 __attribute__((ext_vector_type(4)));

__device__ __forceinline__ unsigned short f2h_bits(float f) {
    _Float16 h = (_Float16)f;
    return __builtin_bit_cast(unsigned short, h);
}
__device__ __forceinline__ float sigmoidf(float x) { return 1.0f / (1.0f + expf(-x)); }

// ---------------------------------------------------------------------------
// Merged setup (1 block x 256): phase 1 computes smg (128x64 row-softmax of
// csl) and csmg (64x16 row-softmax of cls) into PADDED LDS (stride 65 / 17
// to avoid the 32-way same-bank alias the k-strided dot reads would hit),
// plus tbl; __syncthreads; phase 2 emits all frag tables + row0 from LDS.
// Formulas are verbatim from the verified R1 setup_a/setup_b with
// smg[a*64+n] -> sm[a*65+n], csmg[a*16+n] -> cs[a*17+n].
// Replaces two kernel launches with one.
// ---------------------------------------------------------------------------
__global__ __launch_bounds__(256)
void fractal_setup(const float* __restrict__ csl, const float* __restrict__ cls,
                   const float* __restrict__ sp, const float* __restrict__ sdl,
                   float* __restrict__ csmg_g, float* __restrict__ tbl,
                   unsigned short* __restrict__ frag_out, float* __restrict__ row0) {
    __shared__ float sm[128 * 65];
    __shared__ float cs[64 * 17];
    const int tid = threadIdx.x;
    const int w = tid >> 6;
    const int lane = tid & 63;

    // Phase 1a: smg rows (wave-parallel, 32 rows per wave)
    for (int r = w; r < 128; r += 4) {
        const int node = r & 63;
        const int side = r >> 6;
        const float v = csl[node * 128 + side * 64 + lane];
        float mx = v;
#pragma unroll
        for (int msk = 1; msk < 64; msk <<= 1) mx = fmaxf(mx, __shfl_xor(mx, msk, 64));
        const float e = expf(v - mx);
        float sum = e;
#pragma unroll
        for (int msk = 1; msk < 64; msk <<= 1) sum += __shfl_xor(sum, msk, 64);
        sm[r * 65 + lane] = e / sum;
    }
    // Phase 1b: csmg (threads 0..63, verbatim serial softmax), tbl (128..255)
    if (tid < 64) {
        const float* rowp = cls + tid * 16;
        float mx = -1e30f;
        for (int j = 0; j < 16; ++j) mx = fmaxf(mx, rowp[j]);
        float ssum = 0.f;
        for (int j = 0; j < 16; ++j) ssum += expf(rowp[j] - mx);
        const float inv = 1.0f / ssum;
        for (int j = 0; j < 16; ++j) {
            const float pv = expf(rowp[j] - mx) * inv;
            cs[tid * 17 + j] = pv;
            csmg_g[tid * 16 + j] = pv;
        }
    } else if (tid >= 128 && tid < 192) {
        tbl[tid - 128] = expf(-sp[tid - 128]);
    } else if (tid >= 192) {
        tbl[64 + tid - 192] = sigmoidf(sdl[tid - 192]);
    }
    __syncthreads();

    // Phase 2: all frag tables + row0 from LDS (verbatim setup_b formulas)
    for (int e = tid; e < 11392; e += 256) {
        if (e < 8192) {
            const int j = e & 7;
            const int l = (e >> 3) & 63;
            const int fi = e >> 9;
            const int t = fi >> 2, c = fi & 3;
            const int i = l & 15;
            const int n = 8 * (i >> 2) + (i & 3) + 4 * (t & 1) + 32 * (t >> 1);  // tau(t,i)
            const int k0 = (c & 1) * 32 + (l >> 4) * 8 + j;   // node index 0..63
            float v;
            if (c < 2) v = sm[(64 + k0) * 65 + n];                           // R
            else       v = sm[k0 * 65 + n] - sm[(64 + k0) * 65 + n];         // L - R
            frag_out[e] = f2h_bits(v);
        } else if (e < 9216) {
            const int e2 = e - 8192;   // plain Csm frags (md==0/legacy)
            const int j = e2 & 7;
            const int l = (e2 >> 3) & 63;
            const int c = e2 >> 9;
            const int n = l & 15;
            const int k = c * 32 + (l >> 4) * 8 + j;
            frag_out[8192 + e2] = f2h_bits(cs[k * 17 + n]);
        } else if (e < 11264) {
            // Fused final-step frags: RC = R@Csm, LmRC = (L-R)@Csm
            const int e3 = e - 9216;            // 0..2047
            const int f = e3 >> 9;              // 0..3
            const int rem = e3 & 511;
            const int j = rem & 7;
            const int l = (rem >> 3) & 63;
            const int clsx = l & 15;
            const int k = (f & 1) * 32 + ((l >> 4) << 3) + j;   // node 0..63
            float acc = 0.f;
            if (f < 2) {
                for (int n = 0; n < 64; ++n)
                    acc += sm[(64 + k) * 65 + n] * cs[n * 17 + clsx];
            } else {
                for (int n = 0; n < 64; ++n)
                    acc += (sm[k * 65 + n] - sm[(64 + k) * 65 + n]) * cs[n * 17 + clsx];
            }
            frag_out[9216 + e3] = f2h_bits(acc);
        } else {
            const int e2 = e - 11264;           // 0..127
            // row0[k] = R[0,k]; row0[64+k] = L[0,k] - R[0,k]
            row0[e2] = (e2 < 64) ? sm[64 * 65 + e2]
                                 : (sm[(e2 - 64)] - sm[64 * 65 + (e2 - 64)]);
        }
    }
}

// One depth step for both chains (verified R11 body, factored for unrolling).
__device__ __forceinline__ void fractal_step(const f16x8 (&bfr)[4][4],
                                             const f16x8& lfA0, const f16x8& lfA1,
                                             const f16x8& lfB0, const f16x8& lfB1,
                                             i32x4& puA0, i32x4& puA1,
                                             i32x4& puB0, i32x4& puB1) {
    const f16x8 pfA0 = __builtin_bit_cast(f16x8, puA0);
    const f16x8 pfA1 = __builtin_bit_cast(f16x8, puA1);
    const f16x8 pfB0 = __builtin_bit_cast(f16x8, puB0);
    const f16x8 pfB1 = __builtin_bit_cast(f16x8, puB1);
    const f16x8 aA0 = pfA0 * lfA0;   // v_pk_mul_f16
    const f16x8 aA1 = pfA1 * lfA1;
    const f16x8 aB0 = pfB0 * lfB0;
    const f16x8 aB1 = pfB1 * lfB1;
    int PA[4], QA[4], PB[4], QB[4];
#pragma unroll
    for (int t = 0; t < 4; ++t) {
        f32x4 CA = {0.f, 0.f, 0.f, 0.f};
        f32x4 CB = {0.f, 0.f, 0.f, 0.f};
        CA = __builtin_amdgcn_mfma_f32_16x16x32_f16(bfr[t][0], pfA0, CA, 0, 0, 0);
        CB = __builtin_amdgcn_mfma_f32_16x16x32_f16(bfr[t][0], pfB0, CB, 0, 0, 0);
        CA = __builtin_amdgcn_mfma_f32_16x16x32_f16(bfr[t][1], pfA1, CA, 0, 0, 0);
        CB = __builtin_amdgcn_mfma_f32_16x16x32_f16(bfr[t][1], pfB1, CB, 0, 0, 0);
        CA = __builtin_amdgcn_mfma_f32_16x16x32_f16(bfr[t][2], aA0, CA, 0, 0, 0);
        CB = __builtin_amdgcn_mfma_f32_16x16x32_f16(bfr[t][2], aB0, CB, 0, 0, 0);
        CA = __builtin_amdgcn_mfma_f32_16x16x32_f16(bfr[t][3], aA1, CA, 0, 0, 0);
        CB = __builtin_amdgcn_mfma_f32_16x16x32_f16(bfr[t][3], aB1, CB, 0, 0, 0);
        PA[t] = __builtin_bit_cast(int, __builtin_amdgcn_cvt_pkrtz(CA[0], CA[1]));
        QA[t] = __builtin_bit_cast(int, __builtin_amdgcn_cvt_pkrtz(CA[2], CA[3]));
        PB[t] = __builtin_bit_cast(int, __builtin_amdgcn_cvt_pkrtz(CB[0], CB[1]));
        QB[t] = __builtin_bit_cast(int, __builtin_amdgcn_cvt_pkrtz(CB[2], CB[3]));
    }
    // tau labeling: pure register renaming into next state
    puA0.x = PA[0]; puA0.y = QA[0]; puA0.z = PA[1]; puA0.w = QA[1];
    puA1.x = PA[2]; puA1.y = QA[2]; puA1.z = PA[3]; puA1.w = QA[3];
    puB0.x = PB[0]; puB0.y = QB[0]; puB0.z = PB[1]; puB0.w = QB[1];
    puB1.x = PB[2]; puB1.y = QB[2]; puB1.z = PB[3]; puB1.w = QB[3];
}

// ---------------------------------------------------------------------------
// Main: exact R1 body, (256,2). R0-R6 map: alloc cap = 256/min_waves
// (2->128 fits our 76; 4->64 and 6->42 both spill the 64-reg bfr ->
// 2.5-12x regressions). Occupancy is schedulable higher only below the
// 64-reg bucket, which this register-resident structure cannot reach;
// (256,2)/VGPR-76 is the verified local optimum for this main.
// ---------------------------------------------------------------------------
__global__ __launch_bounds__(256, 2)
void fractal_main(const float* __restrict__ x_pos, const float* __restrict__ y_pos,
                  const int* __restrict__ mdp,
                  const unsigned short* __restrict__ frags,
                  const float* __restrict__ tbl,
                  const float* __restrict__ row0,
                  const float* __restrict__ csmg,
                  float* __restrict__ out) {
    const int tid = threadIdx.x;
    const int w = tid >> 6;
    const int l = tid & 63;
    const int q = l >> 4;
    const int m = l & 15;
    const int rowbase = (blockIdx.x * 4 + w) * 32;   // 32 points per wave

    const int md = mdp[0];
    if (md == 0) {
        // p = e0 -> out = Csm[0,:] for every point (then normalize).
        const f32x4 cv = *(const f32x4*)(csmg + 4 * q);
        float s = cv[0] + cv[1] + cv[2] + cv[3];
        s += __shfl_xor(s, 16, 64);
        s += __shfl_xor(s, 32, 64);
        const float inv = 1.0f / fmaxf(s, 1e-10f);
        f32x4 res;
#pragma unroll
        for (int r = 0; r < 4; ++r) res[r] = cv[r] * inv;
        *(f32x4*)(out + (rowbase + m) * 16 + 4 * q) = res;
        *(f32x4*)(out + (rowbase + 16 + m) * 16 + 4 * q) = res;
        return;
    }

    // Resident fragments: [R; L-R] (64 VGPRs), shared by both chains
    const f16x8* __restrict__ fgp = (const f16x8*)frags;
    f16x8 bfr[4][4];
#pragma unroll
    for (int t = 0; t < 4; ++t)
#pragma unroll
        for (int c = 0; c < 4; ++c) bfr[t][c] = fgp[(t * 4 + c) * 64 + l];

    // Vectorized tbl loads
    f32x4 tE0[2], tE1[2], tD0[2], tD1[2];
    tE0[0] = *(const f32x4*)(tbl + 8 * q);       tE0[1] = *(const f32x4*)(tbl + 8 * q + 4);
    tE1[0] = *(const f32x4*)(tbl + 32 + 8 * q);  tE1[1] = *(const f32x4*)(tbl + 32 + 8 * q + 4);
    tD0[0] = *(const f32x4*)(tbl + 64 + 8 * q);  tD0[1] = *(const f32x4*)(tbl + 64 + 8 * q + 4);
    tD1[0] = *(const f32x4*)(tbl + 96 + 8 * q);  tD1[1] = *(const f32x4*)(tbl + 96 + 8 * q + 4);

    const float xA = x_pos[rowbase + m],      yA = y_pos[rowbase + m];
    const float xB = x_pos[rowbase + 16 + m], yB = y_pos[rowbase + 16 + m];
    const float exA = __expf(xA), eyA = __expf(yA);
    const float exB = __expf(xB), eyB = __expf(yB);

    f16x8 lfA0, lfA1, lfB0, lfB1;
#pragma unroll
    for (int j = 0; j < 8; ++j) {
        const float E0 = tE0[j >> 2][j & 3];
        const float E1 = tE1[j >> 2][j & 3];
        const float d0 = tD0[j >> 2][j & 3];
        const float d1 = tD1[j >> 2][j & 3];
        {
            const float h0 = __builtin_amdgcn_rcpf(__builtin_fmaf(exA, E0, 1.0f));
            const float v0 = __builtin_amdgcn_rcpf(__builtin_fmaf(eyA, E0, 1.0f));
            const float h1 = __builtin_amdgcn_rcpf(__builtin_fmaf(exA, E1, 1.0f));
            const float v1 = __builtin_amdgcn_rcpf(__builtin_fmaf(eyA, E1, 1.0f));
            lfA0[j] = (_Float16)(h0 + d0 * (v0 - h0));
            lfA1[j] = (_Float16)(h1 + d1 * (v1 - h1));
        }
        {
            const float h0 = __builtin_amdgcn_rcpf(__builtin_fmaf(exB, E0, 1.0f));
            const float v0 = __builtin_amdgcn_rcpf(__builtin_fmaf(eyB, E0, 1.0f));
            const float h1 = __builtin_amdgcn_rcpf(__builtin_fmaf(exB, E1, 1.0f));
            const float v1 = __builtin_amdgcn_rcpf(__builtin_fmaf(eyB, E1, 1.0f));
            lfB0[j] = (_Float16)(h0 + d0 * (v0 - h0));
            lfB1[j] = (_Float16)(h1 + d1 * (v1 - h1));
        }
    }

    i32x4 puA0, puA1, puB0, puB1;
    if (md >= 2) {
        // Direct step-1 init: p1[k] = R[0,k] + left[b,0]*(L-R)[0,k]
        const float E00 = tbl[0];    // exp(-sp[0])
        const float dir0 = tbl[64];  // sigmoid(sdl[0])
        float lA, lB;
        {
            const float h = __builtin_amdgcn_rcpf(__builtin_fmaf(exA, E00, 1.0f));
            const float v = __builtin_amdgcn_rcpf(__builtin_fmaf(eyA, E00, 1.0f));
            lA = h + dir0 * (v - h);
        }
        {
            const float h = __builtin_amdgcn_rcpf(__builtin_fmaf(exB, E00, 1.0f));
            const float v = __builtin_amdgcn_rcpf(__builtin_fmaf(eyB, E00, 1.0f));
            lB = h + dir0 * (v - h);
        }
        f32x4 rRa[2], rRb[2], rDa[2], rDb[2];
        rRa[0] = *(const f32x4*)(row0 + 8 * q);       rRa[1] = *(const f32x4*)(row0 + 8 * q + 4);
        rRb[0] = *(const f32x4*)(row0 + 32 + 8 * q);  rRb[1] = *(const f32x4*)(row0 + 32 + 8 * q + 4);
        rDa[0] = *(const f32x4*)(row0 + 64 + 8 * q);  rDa[1] = *(const f32x4*)(row0 + 64 + 8 * q + 4);
        rDb[0] = *(const f32x4*)(row0 + 96 + 8 * q);  rDb[1] = *(const f32x4*)(row0 + 96 + 8 * q + 4);
        f16x8 pA0, pA1, pB0, pB1;
#pragma unroll
        for (int j = 0; j < 8; ++j) {
            const float R0 = rRa[j >> 2][j & 3], R1 = rRb[j >> 2][j & 3];
            const float D0 = rDa[j >> 2][j & 3], D1 = rDb[j >> 2][j & 3];
            pA0[j] = (_Float16)__builtin_fmaf(lA, D0, R0);
            pA1[j] = (_Float16)__builtin_fmaf(lA, D1, R1);
            pB0[j] = (_Float16)__builtin_fmaf(lB, D0, R0);
            pB1[j] = (_Float16)__builtin_fmaf(lB, D1, R1);
        }
        puA0 = __builtin_bit_cast(i32x4, pA0);
        puA1 = __builtin_bit_cast(i32x4, pA1);
        puB0 = __builtin_bit_cast(i32x4, pB0);
        puB1 = __builtin_bit_cast(i32x4, pB1);

        if (md == 10) {
#pragma unroll
            for (int d = 0; d < 8; ++d)
                fractal_step(bfr, lfA0, lfA1, lfB0, lfB1, puA0, puA1, puB0, puB1);
        } else {
            for (int d = 0; d < md - 2; ++d)
                fractal_step(bfr, lfA0, lfA1, lfB0, lfB1, puA0, puA1, puB0, puB1);
        }
    } else {  // md == 1: p = e0, fused final does step 1 + projection
        puA0 = (i32x4){0, 0, 0, 0}; puA1 = (i32x4){0, 0, 0, 0};
        puB0 = (i32x4){0, 0, 0, 0}; puB1 = (i32x4){0, 0, 0, 0};
        if (q == 0) { puA0.x = 0x3C00; puB0.x = 0x3C00; }   // f16(1.0)
    }

    // Fused final step + class projection: out^T = [RC; LmRC]^T applied to
    // [p; p*left]. Load fused frags only now (not loop-live).
    f16x8 bfin[4];
#pragma unroll
    for (int f = 0; f < 4; ++f) bfin[f] = fgp[1152 + f * 64 + l];

    {
        const f16x8 pf0 = __builtin_bit_cast(f16x8, puA0);
        const f16x8 pf1 = __builtin_bit_cast(f16x8, puA1);
        const f16x8 a0 = pf0 * lfA0;
        const f16x8 a1 = pf1 * lfA1;
        f32x4 o = {0.f, 0.f, 0.f, 0.f};
        o = __builtin_amdgcn_mfma_f32_16x16x32_f16(bfin[0], pf0, o, 0, 0, 0);
        o = __builtin_amdgcn_mfma_f32_16x16x32_f16(bfin[1], pf1, o, 0, 0, 0);
        o = __builtin_amdgcn_mfma_f32_16x16x32_f16(bfin[2], a0, o, 0, 0, 0);
        o = __builtin_amdgcn_mfma_f32_16x16x32_f16(bfin[3], a1, o, 0, 0, 0);
        float s = o[0] + o[1] + o[2] + o[3];
        s += __shfl_xor(s, 16, 64);
        s += __shfl_xor(s, 32, 64);
        const float inv = 1.0f / fmaxf(s, 1e-10f);
        f32x4 res;
#pragma unroll
        for (int r = 0; r < 4; ++r) res[r] = o[r] * inv;
        *(f32x4*)(out + (rowbase + m) * 16 + 4 * q) = res;
    }
    {
        const f16x8 pf0 = __builtin_bit_cast(f16x8, puB0);
        const f16x8 pf1 = __builtin_bit_cast(f16x8, puB1);
        const f16x8 a0 = pf0 * lfB0;
        const f16x8 a1 = pf1 * lfB1;
        f32x4 o = {0.f, 0.f, 0.f, 0.f};
        o = __builtin_amdgcn_mfma_f32_16x16x32_f16(bfin[0], pf0, o, 0, 0, 0);
        o = __builtin_amdgcn_mfma_f32_16x16x32_f16(bfin[1], pf1, o, 0, 0, 0);
        o = __builtin_amdgcn_mfma_f32_16x16x32_f16(bfin[2], a0, o, 0, 0, 0);
        o = __builtin_amdgcn_mfma_f32_16x16x32_f16(bfin[3], a1, o, 0, 0, 0);
        float s = o[0] + o[1] + o[2] + o[3];
        s += __shfl_xor(s, 16, 64);
        s += __shfl_xor(s, 32, 64);
        const float inv = 1.0f / fmaxf(s, 1e-10f);
        f32x4 res;
#pragma unroll
        for (int r = 0; r < 4; ++r) res[r] = o[r] * inv;
        *(f32x4*)(out + (rowbase + 16 + m) * 16 + 4 * q) = res;
    }
}

extern "C" void kernel_launch(void* const* d_in, const int* in_sizes, int n_in,
                              void* d_out, int out_size, void* d_ws, size_t ws_size,
                              hipStream_t stream) {
    const float* x_pos = (const float*)d_in[0];
    const float* y_pos = (const float*)d_in[1];
    const float* sp    = (const float*)d_in[2];
    const float* sdl   = (const float*)d_in[3];
    const float* cls   = (const float*)d_in[4];
    const float* csl   = (const float*)d_in[5];
    const int*   mdp   = (const int*)d_in[6];

    // d_ws layout:
    //  [0,      22528) frags: 16 main + 2 csm + 4 fused = 11264 halves
    //  [22528,  23040) tbl   (128 f32)
    //  [23040,  23552) row0  (128 f32)
    //  [56320,  60416) csmg  (64x16 f32)   (smg region retired — LDS-only now)
    unsigned short* frags = (unsigned short*)d_ws;
    float* tbl  = (float*)((char*)d_ws + 22528);
    float* row0 = (float*)((char*)d_ws + 23040);
    float* csmg = (float*)((char*)d_ws + 56320);

    fractal_setup<<<1, 256, 0, stream>>>(csl, cls, sp, sdl, csmg, tbl, frags, row0);

    const int B = in_sizes[0];  // 1048576 points; 128 points per block
    fractal_main<<<B / 128, 256, 0, stream>>>(x_pos, y_pos, mdp, frags, tbl, row0,
                                              csmg, (float*)d_out);
}

// Round 8
// 210.790 us; speedup vs baseline: 7.0825x; 1.0523x over previous
//
#include <hip/hip_runtime.h>

typedef float f32x4 __attribute__((ext_vector_type(4)));
typedef _Float16 f16x8 __attribute__((ext_vector_type(8)));
typedef int i32x4 __attribute__((ext_vector_type(4)));

__device__ __forceinline__ unsigned short f2h_bits(float f) {
    _Float16 h = (_Float16)f;
    return __builtin_bit_cast(unsigned short, h);
}
__device__ __forceinline__ float sigmoidf(float x) { return 1.0f / (1.0f + expf(-x)); }

// ---------------------------------------------------------------------------
// Single-launch setup, 45 blocks x 256 (R7 fix): R7's 1-block merged setup was
// latency-bound (1 wave/SIMD on one CU -> the 2048 fused 64-iter LDS dots ran
// at ~120cyc/read with nothing to hide latency; +31us vs the old 2-kernel
// pair). Here EVERY block redundantly computes phase 1 (smg/csmg row-softmax,
// ~1-2us, wave-parallel) into its own padded LDS, then phase 2 uses the exact
// verified R1 setup_b one-element-per-thread slicing (e = bid*256 + tid)
// across 45 blocks — full parallelism restored, still one launch (no
// cross-kernel smg dependency). Block 0 additionally writes tbl + csmg.
// ---------------------------------------------------------------------------
__global__ __launch_bounds__(256)
void fractal_setup(const float* __restrict__ csl, const float* __restrict__ cls,
                   const float* __restrict__ sp, const float* __restrict__ sdl,
                   float* __restrict__ csmg_g, float* __restrict__ tbl,
                   unsigned short* __restrict__ frag_out, float* __restrict__ row0) {
    __shared__ float sm[128 * 65];
    __shared__ float cs[64 * 17];
    const int tid = threadIdx.x;
    const int w = tid >> 6;
    const int lane = tid & 63;

    // Phase 1a: smg rows (wave-parallel, 32 rows per wave) — every block.
    for (int r = w; r < 128; r += 4) {
        const int node = r & 63;
        const int side = r >> 6;
        const float v = csl[node * 128 + side * 64 + lane];
        float mx = v;
#pragma unroll
        for (int msk = 1; msk < 64; msk <<= 1) mx = fmaxf(mx, __shfl_xor(mx, msk, 64));
        const float e = expf(v - mx);
        float sum = e;
#pragma unroll
        for (int msk = 1; msk < 64; msk <<= 1) sum += __shfl_xor(sum, msk, 64);
        sm[r * 65 + lane] = e / sum;
    }
    // Phase 1b: csmg (threads 0..63) — every block (cs feeds phase 2).
    // tbl + csmg_g global writes: block 0 only.
    if (tid < 64) {
        const float* rowp = cls + tid * 16;
        float mx = -1e30f;
        for (int j = 0; j < 16; ++j) mx = fmaxf(mx, rowp[j]);
        float ssum = 0.f;
        for (int j = 0; j < 16; ++j) ssum += expf(rowp[j] - mx);
        const float inv = 1.0f / ssum;
        for (int j = 0; j < 16; ++j) {
            const float pv = expf(rowp[j] - mx) * inv;
            cs[tid * 17 + j] = pv;
            if (blockIdx.x == 0) csmg_g[tid * 16 + j] = pv;
        }
    } else if (blockIdx.x == 0 && tid >= 128 && tid < 192) {
        tbl[tid - 128] = expf(-sp[tid - 128]);
    } else if (blockIdx.x == 0 && tid >= 192) {
        tbl[64 + tid - 192] = sigmoidf(sdl[tid - 192]);
    }
    __syncthreads();

    // Phase 2: exact R1 setup_b mapping — one element per thread.
    const int e = blockIdx.x * 256 + tid;
    if (e < 8192) {
        const int j = e & 7;
        const int l = (e >> 3) & 63;
        const int fi = e >> 9;
        const int t = fi >> 2, c = fi & 3;
        const int i = l & 15;
        const int n = 8 * (i >> 2) + (i & 3) + 4 * (t & 1) + 32 * (t >> 1);  // tau(t,i)
        const int k0 = (c & 1) * 32 + (l >> 4) * 8 + j;   // node index 0..63
        float v;
        if (c < 2) v = sm[(64 + k0) * 65 + n];                           // R
        else       v = sm[k0 * 65 + n] - sm[(64 + k0) * 65 + n];         // L - R
        frag_out[e] = f2h_bits(v);
    } else if (e < 9216) {
        const int e2 = e - 8192;   // plain Csm frags (md==0/legacy)
        const int j = e2 & 7;
        const int l = (e2 >> 3) & 63;
        const int c = e2 >> 9;
        const int n = l & 15;
        const int k = c * 32 + (l >> 4) * 8 + j;
        frag_out[8192 + e2] = f2h_bits(cs[k * 17 + n]);
    } else if (e < 11264) {
        // Fused final-step frags: RC = R@Csm, LmRC = (L-R)@Csm
        const int e3 = e - 9216;            // 0..2047
        const int f = e3 >> 9;              // 0..3
        const int rem = e3 & 511;
        const int j = rem & 7;
        const int l = (rem >> 3) & 63;
        const int clsx = l & 15;
        const int k = (f & 1) * 32 + ((l >> 4) << 3) + j;   // node 0..63
        float acc = 0.f;
        if (f < 2) {
            for (int n = 0; n < 64; ++n)
                acc += sm[(64 + k) * 65 + n] * cs[n * 17 + clsx];
        } else {
            for (int n = 0; n < 64; ++n)
                acc += (sm[k * 65 + n] - sm[(64 + k) * 65 + n]) * cs[n * 17 + clsx];
        }
        frag_out[9216 + e3] = f2h_bits(acc);
    } else if (e < 11392) {
        const int e2 = e - 11264;           // 0..127
        // row0[k] = R[0,k]; row0[64+k] = L[0,k] - R[0,k]
        row0[e2] = (e2 < 64) ? sm[64 * 65 + e2]
                             : (sm[(e2 - 64)] - sm[64 * 65 + (e2 - 64)]);
    }
}

// One depth step for both chains (verified R11 body, factored for unrolling).
__device__ __forceinline__ void fractal_step(const f16x8 (&bfr)[4][4],
                                             const f16x8& lfA0, const f16x8& lfA1,
                                             const f16x8& lfB0, const f16x8& lfB1,
                                             i32x4& puA0, i32x4& puA1,
                                             i32x4& puB0, i32x4& puB1) {
    const f16x8 pfA0 = __builtin_bit_cast(f16x8, puA0);
    const f16x8 pfA1 = __builtin_bit_cast(f16x8, puA1);
    const f16x8 pfB0 = __builtin_bit_cast(f16x8, puB0);
    const f16x8 pfB1 = __builtin_bit_cast(f16x8, puB1);
    const f16x8 aA0 = pfA0 * lfA0;   // v_pk_mul_f16
    const f16x8 aA1 = pfA1 * lfA1;
    const f16x8 aB0 = pfB0 * lfB0;
    const f16x8 aB1 = pfB1 * lfB1;
    int PA[4], QA[4], PB[4], QB[4];
#pragma unroll
    for (int t = 0; t < 4; ++t) {
        f32x4 CA = {0.f, 0.f, 0.f, 0.f};
        f32x4 CB = {0.f, 0.f, 0.f, 0.f};
        CA = __builtin_amdgcn_mfma_f32_16x16x32_f16(bfr[t][0], pfA0, CA, 0, 0, 0);
        CB = __builtin_amdgcn_mfma_f32_16x16x32_f16(bfr[t][0], pfB0, CB, 0, 0, 0);
        CA = __builtin_amdgcn_mfma_f32_16x16x32_f16(bfr[t][1], pfA1, CA, 0, 0, 0);
        CB = __builtin_amdgcn_mfma_f32_16x16x32_f16(bfr[t][1], pfB1, CB, 0, 0, 0);
        CA = __builtin_amdgcn_mfma_f32_16x16x32_f16(bfr[t][2], aA0, CA, 0, 0, 0);
        CB = __builtin_amdgcn_mfma_f32_16x16x32_f16(bfr[t][2], aB0, CB, 0, 0, 0);
        CA = __builtin_amdgcn_mfma_f32_16x16x32_f16(bfr[t][3], aA1, CA, 0, 0, 0);
        CB = __builtin_amdgcn_mfma_f32_16x16x32_f16(bfr[t][3], aB1, CB, 0, 0, 0);
        PA[t] = __builtin_bit_cast(int, __builtin_amdgcn_cvt_pkrtz(CA[0], CA[1]));
        QA[t] = __builtin_bit_cast(int, __builtin_amdgcn_cvt_pkrtz(CA[2], CA[3]));
        PB[t] = __builtin_bit_cast(int, __builtin_amdgcn_cvt_pkrtz(CB[0], CB[1]));
        QB[t] = __builtin_bit_cast(int, __builtin_amdgcn_cvt_pkrtz(CB[2], CB[3]));
    }
    // tau labeling: pure register renaming into next state
    puA0.x = PA[0]; puA0.y = QA[0]; puA0.z = PA[1]; puA0.w = QA[1];
    puA1.x = PA[2]; puA1.y = QA[2]; puA1.z = PA[3]; puA1.w = QA[3];
    puB0.x = PB[0]; puB0.y = QB[0]; puB0.z = PB[1]; puB0.w = QB[1];
    puB1.x = PB[2]; puB1.y = QB[2]; puB1.z = PB[3]; puB1.w = QB[3];
}

// ---------------------------------------------------------------------------
// Main: exact R1 body, (256,2) — verified local optimum (VGPR 76, ~121.5us).
// Alloc cap map (R0-R6): 256/min_waves -> only min=2 avoids spilling the
// 64-reg bfr; higher declared residency spills (2.5-12x regressions).
// ---------------------------------------------------------------------------
__global__ __launch_bounds__(256, 2)
void fractal_main(const float* __restrict__ x_pos, const float* __restrict__ y_pos,
                  const int* __restrict__ mdp,
                  const unsigned short* __restrict__ frags,
                  const float* __restrict__ tbl,
                  const float* __restrict__ row0,
                  const float* __restrict__ csmg,
                  float* __restrict__ out) {
    const int tid = threadIdx.x;
    const int w = tid >> 6;
    const int l = tid & 63;
    const int q = l >> 4;
    const int m = l & 15;
    const int rowbase = (blockIdx.x * 4 + w) * 32;   // 32 points per wave

    const int md = mdp[0];
    if (md == 0) {
        // p = e0 -> out = Csm[0,:] for every point (then normalize).
        const f32x4 cv = *(const f32x4*)(csmg + 4 * q);
        float s = cv[0] + cv[1] + cv[2] + cv[3];
        s += __shfl_xor(s, 16, 64);
        s += __shfl_xor(s, 32, 64);
        const float inv = 1.0f / fmaxf(s, 1e-10f);
        f32x4 res;
#pragma unroll
        for (int r = 0; r < 4; ++r) res[r] = cv[r] * inv;
        *(f32x4*)(out + (rowbase + m) * 16 + 4 * q) = res;
        *(f32x4*)(out + (rowbase + 16 + m) * 16 + 4 * q) = res;
        return;
    }

    // Resident fragments: [R; L-R] (64 VGPRs), shared by both chains
    const f16x8* __restrict__ fgp = (const f16x8*)frags;
    f16x8 bfr[4][4];
#pragma unroll
    for (int t = 0; t < 4; ++t)
#pragma unroll
        for (int c = 0; c < 4; ++c) bfr[t][c] = fgp[(t * 4 + c) * 64 + l];

    // Vectorized tbl loads
    f32x4 tE0[2], tE1[2], tD0[2], tD1[2];
    tE0[0] = *(const f32x4*)(tbl + 8 * q);       tE0[1] = *(const f32x4*)(tbl + 8 * q + 4);
    tE1[0] = *(const f32x4*)(tbl + 32 + 8 * q);  tE1[1] = *(const f32x4*)(tbl + 32 + 8 * q + 4);
    tD0[0] = *(const f32x4*)(tbl + 64 + 8 * q);  tD0[1] = *(const f32x4*)(tbl + 64 + 8 * q + 4);
    tD1[0] = *(const f32x4*)(tbl + 96 + 8 * q);  tD1[1] = *(const f32x4*)(tbl + 96 + 8 * q + 4);

    const float xA = x_pos[rowbase + m],      yA = y_pos[rowbase + m];
    const float xB = x_pos[rowbase + 16 + m], yB = y_pos[rowbase + 16 + m];
    const float exA = __expf(xA), eyA = __expf(yA);
    const float exB = __expf(xB), eyB = __expf(yB);

    f16x8 lfA0, lfA1, lfB0, lfB1;
#pragma unroll
    for (int j = 0; j < 8; ++j) {
        const float E0 = tE0[j >> 2][j & 3];
        const float E1 = tE1[j >> 2][j & 3];
        const float d0 = tD0[j >> 2][j & 3];
        const float d1 = tD1[j >> 2][j & 3];
        {
            const float h0 = __builtin_amdgcn_rcpf(__builtin_fmaf(exA, E0, 1.0f));
            const float v0 = __builtin_amdgcn_rcpf(__builtin_fmaf(eyA, E0, 1.0f));
            const float h1 = __builtin_amdgcn_rcpf(__builtin_fmaf(exA, E1, 1.0f));
            const float v1 = __builtin_amdgcn_rcpf(__builtin_fmaf(eyA, E1, 1.0f));
            lfA0[j] = (_Float16)(h0 + d0 * (v0 - h0));
            lfA1[j] = (_Float16)(h1 + d1 * (v1 - h1));
        }
        {
            const float h0 = __builtin_amdgcn_rcpf(__builtin_fmaf(exB, E0, 1.0f));
            const float v0 = __builtin_amdgcn_rcpf(__builtin_fmaf(eyB, E0, 1.0f));
            const float h1 = __builtin_amdgcn_rcpf(__builtin_fmaf(exB, E1, 1.0f));
            const float v1 = __builtin_amdgcn_rcpf(__builtin_fmaf(eyB, E1, 1.0f));
            lfB0[j] = (_Float16)(h0 + d0 * (v0 - h0));
            lfB1[j] = (_Float16)(h1 + d1 * (v1 - h1));
        }
    }

    i32x4 puA0, puA1, puB0, puB1;
    if (md >= 2) {
        // Direct step-1 init: p1[k] = R[0,k] + left[b,0]*(L-R)[0,k]
        const float E00 = tbl[0];    // exp(-sp[0])
        const float dir0 = tbl[64];  // sigmoid(sdl[0])
        float lA, lB;
        {
            const float h = __builtin_amdgcn_rcpf(__builtin_fmaf(exA, E00, 1.0f));
            const float v = __builtin_amdgcn_rcpf(__builtin_fmaf(eyA, E00, 1.0f));
            lA = h + dir0 * (v - h);
        }
        {
            const float h = __builtin_amdgcn_rcpf(__builtin_fmaf(exB, E00, 1.0f));
            const float v = __builtin_amdgcn_rcpf(__builtin_fmaf(eyB, E00, 1.0f));
            lB = h + dir0 * (v - h);
        }
        f32x4 rRa[2], rRb[2], rDa[2], rDb[2];
        rRa[0] = *(const f32x4*)(row0 + 8 * q);       rRa[1] = *(const f32x4*)(row0 + 8 * q + 4);
        rRb[0] = *(const f32x4*)(row0 + 32 + 8 * q);  rRb[1] = *(const f32x4*)(row0 + 32 + 8 * q + 4);
        rDa[0] = *(const f32x4*)(row0 + 64 + 8 * q);  rDa[1] = *(const f32x4*)(row0 + 64 + 8 * q + 4);
        rDb[0] = *(const f32x4*)(row0 + 96 + 8 * q);  rDb[1] = *(const f32x4*)(row0 + 96 + 8 * q + 4);
        f16x8 pA0, pA1, pB0, pB1;
#pragma unroll
        for (int j = 0; j < 8; ++j) {
            const float R0 = rRa[j >> 2][j & 3], R1 = rRb[j >> 2][j & 3];
            const float D0 = rDa[j >> 2][j & 3], D1 = rDb[j >> 2][j & 3];
            pA0[j] = (_Float16)__builtin_fmaf(lA, D0, R0);
            pA1[j] = (_Float16)__builtin_fmaf(lA, D1, R1);
            pB0[j] = (_Float16)__builtin_fmaf(lB, D0, R0);
            pB1[j] = (_Float16)__builtin_fmaf(lB, D1, R1);
        }
        puA0 = __builtin_bit_cast(i32x4, pA0);
        puA1 = __builtin_bit_cast(i32x4, pA1);
        puB0 = __builtin_bit_cast(i32x4, pB0);
        puB1 = __builtin_bit_cast(i32x4, pB1);

        if (md == 10) {
#pragma unroll
            for (int d = 0; d < 8; ++d)
                fractal_step(bfr, lfA0, lfA1, lfB0, lfB1, puA0, puA1, puB0, puB1);
        } else {
            for (int d = 0; d < md - 2; ++d)
                fractal_step(bfr, lfA0, lfA1, lfB0, lfB1, puA0, puA1, puB0, puB1);
        }
    } else {  // md == 1: p = e0, fused final does step 1 + projection
        puA0 = (i32x4){0, 0, 0, 0}; puA1 = (i32x4){0, 0, 0, 0};
        puB0 = (i32x4){0, 0, 0, 0}; puB1 = (i32x4){0, 0, 0, 0};
        if (q == 0) { puA0.x = 0x3C00; puB0.x = 0x3C00; }   // f16(1.0)
    }

    // Fused final step + class projection: out^T = [RC; LmRC]^T applied to
    // [p; p*left]. Load fused frags only now (not loop-live).
    f16x8 bfin[4];
#pragma unroll
    for (int f = 0; f < 4; ++f) bfin[f] = fgp[1152 + f * 64 + l];

    {
        const f16x8 pf0 = __builtin_bit_cast(f16x8, puA0);
        const f16x8 pf1 = __builtin_bit_cast(f16x8, puA1);
        const f16x8 a0 = pf0 * lfA0;
        const f16x8 a1 = pf1 * lfA1;
        f32x4 o = {0.f, 0.f, 0.f, 0.f};
        o = __builtin_amdgcn_mfma_f32_16x16x32_f16(bfin[0], pf0, o, 0, 0, 0);
        o = __builtin_amdgcn_mfma_f32_16x16x32_f16(bfin[1], pf1, o, 0, 0, 0);
        o = __builtin_amdgcn_mfma_f32_16x16x32_f16(bfin[2], a0, o, 0, 0, 0);
        o = __builtin_amdgcn_mfma_f32_16x16x32_f16(bfin[3], a1, o, 0, 0, 0);
        float s = o[0] + o[1] + o[2] + o[3];
        s += __shfl_xor(s, 16, 64);
        s += __shfl_xor(s, 32, 64);
        const float inv = 1.0f / fmaxf(s, 1e-10f);
        f32x4 res;
#pragma unroll
        for (int r = 0; r < 4; ++r) res[r] = o[r] * inv;
        *(f32x4*)(out + (rowbase + m) * 16 + 4 * q) = res;
    }
    {
        const f16x8 pf0 = __builtin_bit_cast(f16x8, puB0);
        const f16x8 pf1 = __builtin_bit_cast(f16x8, puB1);
        const f16x8 a0 = pf0 * lfB0;
        const f16x8 a1 = pf1 * lfB1;
        f32x4 o = {0.f, 0.f, 0.f, 0.f};
        o = __builtin_amdgcn_mfma_f32_16x16x32_f16(bfin[0], pf0, o, 0, 0, 0);
        o = __builtin_amdgcn_mfma_f32_16x16x32_f16(bfin[1], pf1, o, 0, 0, 0);
        o = __builtin_amdgcn_mfma_f32_16x16x32_f16(bfin[2], a0, o, 0, 0, 0);
        o = __builtin_amdgcn_mfma_f32_16x16x32_f16(bfin[3], a1, o, 0, 0, 0);
        float s = o[0] + o[1] + o[2] + o[3];
        s += __shfl_xor(s, 16, 64);
        s += __shfl_xor(s, 32, 64);
        const float inv = 1.0f / fmaxf(s, 1e-10f);
        f32x4 res;
#pragma unroll
        for (int r = 0; r < 4; ++r) res[r] = o[r] * inv;
        *(f32x4*)(out + (rowbase + 16 + m) * 16 + 4 * q) = res;
    }
}

extern "C" void kernel_launch(void* const* d_in, const int* in_sizes, int n_in,
                              void* d_out, int out_size, void* d_ws, size_t ws_size,
                              hipStream_t stream) {
    const float* x_pos = (const float*)d_in[0];
    const float* y_pos = (const float*)d_in[1];
    const float* sp    = (const float*)d_in[2];
    const float* sdl   = (const float*)d_in[3];
    const float* cls   = (const float*)d_in[4];
    const float* csl   = (const float*)d_in[5];
    const int*   mdp   = (const int*)d_in[6];

    // d_ws layout:
    //  [0,      22528) frags: 16 main + 2 csm + 4 fused = 11264 halves
    //  [22528,  23040) tbl   (128 f32)
    //  [23040,  23552) row0  (128 f32)
    //  [56320,  60416) csmg  (64x16 f32)
    unsigned short* frags = (unsigned short*)d_ws;
    float* tbl  = (float*)((char*)d_ws + 22528);
    float* row0 = (float*)((char*)d_ws + 23040);
    float* csmg = (float*)((char*)d_ws + 56320);

    fractal_setup<<<45, 256, 0, stream>>>(csl, cls, sp, sdl, csmg, tbl, frags, row0);

    const int B = in_sizes[0];  // 1048576 points; 128 points per block
    fractal_main<<<B / 128, 256, 0, stream>>>(x_pos, y_pos, mdp, frags, tbl, row0,
                                              csmg, (float*)d_out);
}

// Round 9
// 191.688 us; speedup vs baseline: 7.7883x; 1.0997x over previous
//
#include <hip/hip_runtime.h>

typedef float f32x4 __attribute__((ext_vector_type(4)));
typedef _Float16 f16x8 __attribute__((ext_vector_type(8)));
typedef int i32x4 __attribute__((ext_vector_type(4)));

__device__ __forceinline__ unsigned short f2h_bits(float f) {
    _Float16 h = (_Float16)f;
    return __builtin_bit_cast(unsigned short, h);
}
__device__ __forceinline__ float sigmoidf(float x) { return 1.0f / (1.0f + expf(-x)); }

// ---------------------------------------------------------------------------
// Setup A (33 blocks x 256) — UNCHANGED verified R1 kernel.
// ---------------------------------------------------------------------------
__global__ void fractal_setup_a(const float* __restrict__ csl, const float* __restrict__ cls,
                                const float* __restrict__ sp, const float* __restrict__ sdl,
                                float* __restrict__ smg, float* __restrict__ csmg,
                                float* __restrict__ tbl) {
    const int tid = threadIdx.x;
    if (blockIdx.x < 32) {
        const int w = tid >> 6;
        const int lane = tid & 63;
        const int r = blockIdx.x * 4 + w;          // 0..127
        const int node = r & 63;
        const int side = r >> 6;
        const float v = csl[node * 128 + side * 64 + lane];
        float mx = v;
#pragma unroll
        for (int msk = 1; msk < 64; msk <<= 1) mx = fmaxf(mx, __shfl_xor(mx, msk, 64));
        const float e = expf(v - mx);
        float sum = e;
#pragma unroll
        for (int msk = 1; msk < 64; msk <<= 1) sum += __shfl_xor(sum, msk, 64);
        smg[r * 64 + lane] = e / sum;
    } else {
        if (tid < 64) {
            const float* rowp = cls + tid * 16;
            float mx = -1e30f;
            for (int j = 0; j < 16; ++j) mx = fmaxf(mx, rowp[j]);
            float ssum = 0.f;
            for (int j = 0; j < 16; ++j) ssum += expf(rowp[j] - mx);
            const float inv = 1.0f / ssum;
            for (int j = 0; j < 16; ++j) csmg[tid * 16 + j] = expf(rowp[j] - mx) * inv;
        } else if (tid >= 128 && tid < 192) {
            tbl[tid - 128] = expf(-sp[tid - 128]);
        } else if (tid >= 192) {
            tbl[64 + tid - 192] = sigmoidf(sdl[tid - 192]);
        }
    }
}

// ---------------------------------------------------------------------------
// Setup B (557 blocks x 256): blocks 0..44 = verbatim verified R1 setup_b
// (frag packing, fused final frags, row0).  Blocks 45..556 fill the NEW
// sigmoid tables H[1024][64], V[1024][64]:
//   H[i][k] = sigmoid(sp[k] - x_i),  V[j][k] = sigmoid(sp[k] - y_j)
// exploiting the meshgrid input (x constant along rows: x_i = x_pos[i*1024],
// y_j = y_pos[j]).  These replace main's per-point 64x rcp sigmoid build
// (the issue-port-bound prologue, ~1/3 of all issue cycles).
// ---------------------------------------------------------------------------
__global__ void fractal_setup_b(const float* __restrict__ smg, const float* __restrict__ csmg,
                                const float* __restrict__ x_pos, const float* __restrict__ y_pos,
                                const float* __restrict__ sp,
                                unsigned short* __restrict__ frag_out,
                                float* __restrict__ row0,
                                float* __restrict__ H, float* __restrict__ V) {
    const int e = blockIdx.x * 256 + threadIdx.x;
    if (e < 8192) {
        const int j = e & 7;
        const int l = (e >> 3) & 63;
        const int fi = e >> 9;
        const int t = fi >> 2, c = fi & 3;
        const int i = l & 15;
        const int n = 8 * (i >> 2) + (i & 3) + 4 * (t & 1) + 32 * (t >> 1);  // tau(t,i)
        const int k0 = (c & 1) * 32 + (l >> 4) * 8 + j;   // node index 0..63
        float v;
        if (c < 2) v = smg[(64 + k0) * 64 + n];                         // R
        else       v = smg[k0 * 64 + n] - smg[(64 + k0) * 64 + n];      // L - R
        frag_out[e] = f2h_bits(v);
    } else if (e < 9216) {
        const int e2 = e - 8192;   // plain Csm frags (md==0/legacy)
        const int j = e2 & 7;
        const int l = (e2 >> 3) & 63;
        const int c = e2 >> 9;
        const int n = l & 15;
        const int k = c * 32 + (l >> 4) * 8 + j;
        frag_out[8192 + e2] = f2h_bits(csmg[k * 16 + n]);
    } else if (e < 11264) {
        // Fused final-step frags: RC = R@Csm, LmRC = (L-R)@Csm
        const int e3 = e - 9216;            // 0..2047
        const int f = e3 >> 9;              // 0..3
        const int rem = e3 & 511;
        const int j = rem & 7;
        const int l = (rem >> 3) & 63;
        const int cls = l & 15;
        const int k = (f & 1) * 32 + ((l >> 4) << 3) + j;   // node 0..63
        float acc = 0.f;
        if (f < 2) {
            for (int n = 0; n < 64; ++n)
                acc += smg[(64 + k) * 64 + n] * csmg[n * 16 + cls];
        } else {
            for (int n = 0; n < 64; ++n)
                acc += (smg[k * 64 + n] - smg[(64 + k) * 64 + n]) * csmg[n * 16 + cls];
        }
        frag_out[9216 + e3] = f2h_bits(acc);
    } else if (e < 11392) {
        const int e2 = e - 11264;           // 0..127
        // row0[k] = R[0,k]; row0[64+k] = L[0,k] - R[0,k]
        row0[e2] = (e2 < 64) ? smg[4096 + e2]
                             : (smg[e2 - 64] - smg[4096 + (e2 - 64)]);
    } else if (e >= 11520) {
        // Sigmoid tables: te in [0, 131072)
        const int te = e - 11520;
        const int t = te >> 16;             // 0 = H (x), 1 = V (y)
        const int idx = te & 65535;
        const int i = idx >> 6;             // grid row/col index 0..1023
        const int k = idx & 63;             // node 0..63
        const float pos = t ? y_pos[i] : x_pos[i << 10];
        const float val = 1.0f / (1.0f + expf(pos - sp[k]));
        (t ? V : H)[i * 64 + k] = val;
    }
}

// One depth step for both chains (verified R11 body, factored for unrolling).
__device__ __forceinline__ void fractal_step(const f16x8 (&bfr)[4][4],
                                             const f16x8& lfA0, const f16x8& lfA1,
                                             const f16x8& lfB0, const f16x8& lfB1,
                                             i32x4& puA0, i32x4& puA1,
                                             i32x4& puB0, i32x4& puB1) {
    const f16x8 pfA0 = __builtin_bit_cast(f16x8, puA0);
    const f16x8 pfA1 = __builtin_bit_cast(f16x8, puA1);
    const f16x8 pfB0 = __builtin_bit_cast(f16x8, puB0);
    const f16x8 pfB1 = __builtin_bit_cast(f16x8, puB1);
    const f16x8 aA0 = pfA0 * lfA0;   // v_pk_mul_f16
    const f16x8 aA1 = pfA1 * lfA1;
    const f16x8 aB0 = pfB0 * lfB0;
    const f16x8 aB1 = pfB1 * lfB1;
    int PA[4], QA[4], PB[4], QB[4];
#pragma unroll
    for (int t = 0; t < 4; ++t) {
        f32x4 CA = {0.f, 0.f, 0.f, 0.f};
        f32x4 CB = {0.f, 0.f, 0.f, 0.f};
        CA = __builtin_amdgcn_mfma_f32_16x16x32_f16(bfr[t][0], pfA0, CA, 0, 0, 0);
        CB = __builtin_amdgcn_mfma_f32_16x16x32_f16(bfr[t][0], pfB0, CB, 0, 0, 0);
        CA = __builtin_amdgcn_mfma_f32_16x16x32_f16(bfr[t][1], pfA1, CA, 0, 0, 0);
        CB = __builtin_amdgcn_mfma_f32_16x16x32_f16(bfr[t][1], pfB1, CB, 0, 0, 0);
        CA = __builtin_amdgcn_mfma_f32_16x16x32_f16(bfr[t][2], aA0, CA, 0, 0, 0);
        CB = __builtin_amdgcn_mfma_f32_16x16x32_f16(bfr[t][2], aB0, CB, 0, 0, 0);
        CA = __builtin_amdgcn_mfma_f32_16x16x32_f16(bfr[t][3], aA1, CA, 0, 0, 0);
        CB = __builtin_amdgcn_mfma_f32_16x16x32_f16(bfr[t][3], aB1, CB, 0, 0, 0);
        PA[t] = __builtin_bit_cast(int, __builtin_amdgcn_cvt_pkrtz(CA[0], CA[1]));
        QA[t] = __builtin_bit_cast(int, __builtin_amdgcn_cvt_pkrtz(CA[2], CA[3]));
        PB[t] = __builtin_bit_cast(int, __builtin_amdgcn_cvt_pkrtz(CB[0], CB[1]));
        QB[t] = __builtin_bit_cast(int, __builtin_amdgcn_cvt_pkrtz(CB[2], CB[3]));
    }
    // tau labeling: pure register renaming into next state
    puA0.x = PA[0]; puA0.y = QA[0]; puA0.z = PA[1]; puA0.w = QA[1];
    puA1.x = PA[2]; puA1.y = QA[2]; puA1.z = PA[3]; puA1.w = QA[3];
    puB0.x = PB[0]; puB0.y = QB[0]; puB0.z = PB[1]; puB0.w = QB[1];
    puB1.x = PB[2]; puB1.y = QB[2]; puB1.z = PB[3]; puB1.w = QB[3];
}

// ---------------------------------------------------------------------------
// Main: R1 body, (256,2), with the lf-sigmoid prologue replaced by table
// loads. Ledger: MfmaUtil+VALUBusy ~ 100-108% across all clean runs => the
// SIMD issue port is saturated; the 64x rcp + 64x fma + 2x expf prologue is
// ~1/3 of per-wave issue cycles. H rows are shared by all 32 points of a
// wave (same x-row => broadcast loads); V rows per-point but L2-resident.
// lf lerp stays f32 + single f16 rounding (same numerics as R1).
// ---------------------------------------------------------------------------
__global__ __launch_bounds__(256, 2)
void fractal_main(const float* __restrict__ x_pos, const float* __restrict__ y_pos,
                  const int* __restrict__ mdp,
                  const unsigned short* __restrict__ frags,
                  const float* __restrict__ tbl,
                  const float* __restrict__ row0,
                  const float* __restrict__ csmg,
                  const float* __restrict__ H, const float* __restrict__ V,
                  float* __restrict__ out) {
    const int tid = threadIdx.x;
    const int w = tid >> 6;
    const int l = tid & 63;
    const int q = l >> 4;
    const int m = l & 15;
    const int rowbase = (blockIdx.x * 4 + w) * 32;   // 32 points per wave

    const int md = mdp[0];
    if (md == 0) {
        const f32x4 cv = *(const f32x4*)(csmg + 4 * q);
        float s = cv[0] + cv[1] + cv[2] + cv[3];
        s += __shfl_xor(s, 16, 64);
        s += __shfl_xor(s, 32, 64);
        const float inv = 1.0f / fmaxf(s, 1e-10f);
        f32x4 res;
#pragma unroll
        for (int r = 0; r < 4; ++r) res[r] = cv[r] * inv;
        *(f32x4*)(out + (rowbase + m) * 16 + 4 * q) = res;
        *(f32x4*)(out + (rowbase + 16 + m) * 16 + 4 * q) = res;
        return;
    }

    // Grid indices: 32-point window never crosses a row (rowbase % 32 == 0).
    const int gi = rowbase >> 10;          // x index (shared by A and B)
    const int gj = rowbase & 1023;         // y base
    const float* __restrict__ Hrow  = H + gi * 64;
    const float* __restrict__ VrowA = V + (gj + m) * 64;
    const float* __restrict__ VrowB = V + (gj + 16 + m) * 64;

    // dirs table (f32x4 vector loads, as R1)
    f32x4 tD0[2], tD1[2];
    tD0[0] = *(const f32x4*)(tbl + 64 + 8 * q);  tD0[1] = *(const f32x4*)(tbl + 64 + 8 * q + 4);
    tD1[0] = *(const f32x4*)(tbl + 96 + 8 * q);  tD1[1] = *(const f32x4*)(tbl + 96 + 8 * q + 4);

    // Sigmoid table slices: nodes 8q+j (bank0) and 32+8q+j (bank1)
    f32x4 hx0[2], hx1[2], vA0[2], vA1[2], vB0[2], vB1[2];
    hx0[0] = *(const f32x4*)(Hrow + 8 * q);       hx0[1] = *(const f32x4*)(Hrow + 8 * q + 4);
    hx1[0] = *(const f32x4*)(Hrow + 32 + 8 * q);  hx1[1] = *(const f32x4*)(Hrow + 32 + 8 * q + 4);
    vA0[0] = *(const f32x4*)(VrowA + 8 * q);      vA0[1] = *(const f32x4*)(VrowA + 8 * q + 4);
    vA1[0] = *(const f32x4*)(VrowA + 32 + 8 * q); vA1[1] = *(const f32x4*)(VrowA + 32 + 8 * q + 4);
    vB0[0] = *(const f32x4*)(VrowB + 8 * q);      vB0[1] = *(const f32x4*)(VrowB + 8 * q + 4);
    vB1[0] = *(const f32x4*)(VrowB + 32 + 8 * q); vB1[1] = *(const f32x4*)(VrowB + 32 + 8 * q + 4);

    f16x8 lfA0, lfA1, lfB0, lfB1;
#pragma unroll
    for (int j = 0; j < 8; ++j) {
        const float d0 = tD0[j >> 2][j & 3];
        const float d1 = tD1[j >> 2][j & 3];
        const float h0 = hx0[j >> 2][j & 3];
        const float h1 = hx1[j >> 2][j & 3];
        lfA0[j] = (_Float16)(h0 + d0 * (vA0[j >> 2][j & 3] - h0));
        lfA1[j] = (_Float16)(h1 + d1 * (vA1[j >> 2][j & 3] - h1));
        lfB0[j] = (_Float16)(h0 + d0 * (vB0[j >> 2][j & 3] - h0));
        lfB1[j] = (_Float16)(h1 + d1 * (vB1[j >> 2][j & 3] - h1));
    }

    // Resident fragments loaded AFTER the lf build to cap peak VGPR liveness
    const f16x8* __restrict__ fgp = (const f16x8*)frags;
    f16x8 bfr[4][4];
#pragma unroll
    for (int t = 0; t < 4; ++t)
#pragma unroll
        for (int c = 0; c < 4; ++c) bfr[t][c] = fgp[(t * 4 + c) * 64 + l];

    i32x4 puA0, puA1, puB0, puB1;
    if (md >= 2) {
        // Direct step-1 init from table node 0: p1 = R[0,:] + left0*(L-R)[0,:]
        const float dir0 = tbl[64];
        const float h00 = Hrow[0];
        const float lA = h00 + dir0 * (VrowA[0] - h00);
        const float lB = h00 + dir0 * (VrowB[0] - h00);
        f32x4 rRa[2], rRb[2], rDa[2], rDb[2];
        rRa[0] = *(const f32x4*)(row0 + 8 * q);       rRa[1] = *(const f32x4*)(row0 + 8 * q + 4);
        rRb[0] = *(const f32x4*)(row0 + 32 + 8 * q);  rRb[1] = *(const f32x4*)(row0 + 32 + 8 * q + 4);
        rDa[0] = *(const f32x4*)(row0 + 64 + 8 * q);  rDa[1] = *(const f32x4*)(row0 + 64 + 8 * q + 4);
        rDb[0] = *(const f32x4*)(row0 + 96 + 8 * q);  rDb[1] = *(const f32x4*)(row0 + 96 + 8 * q + 4);
        f16x8 pA0, pA1, pB0, pB1;
#pragma unroll
        for (int j = 0; j < 8; ++j) {
            const float R0 = rRa[j >> 2][j & 3], R1 = rRb[j >> 2][j & 3];
            const float D0 = rDa[j >> 2][j & 3], D1 = rDb[j >> 2][j & 3];
            pA0[j] = (_Float16)__builtin_fmaf(lA, D0, R0);
            pA1[j] = (_Float16)__builtin_fmaf(lA, D1, R1);
            pB0[j] = (_Float16)__builtin_fmaf(lB, D0, R0);
            pB1[j] = (_Float16)__builtin_fmaf(lB, D1, R1);
        }
        puA0 = __builtin_bit_cast(i32x4, pA0);
        puA1 = __builtin_bit_cast(i32x4, pA1);
        puB0 = __builtin_bit_cast(i32x4, pB0);
        puB1 = __builtin_bit_cast(i32x4, pB1);

        if (md == 10) {
#pragma unroll
            for (int d = 0; d < 8; ++d)
                fractal_step(bfr, lfA0, lfA1, lfB0, lfB1, puA0, puA1, puB0, puB1);
        } else {
            for (int d = 0; d < md - 2; ++d)
                fractal_step(bfr, lfA0, lfA1, lfB0, lfB1, puA0, puA1, puB0, puB1);
        }
    } else {  // md == 1
        puA0 = (i32x4){0, 0, 0, 0}; puA1 = (i32x4){0, 0, 0, 0};
        puB0 = (i32x4){0, 0, 0, 0}; puB1 = (i32x4){0, 0, 0, 0};
        if (q == 0) { puA0.x = 0x3C00; puB0.x = 0x3C00; }   // f16(1.0)
    }

    // Fused final step + class projection.
    f16x8 bfin[4];
#pragma unroll
    for (int f = 0; f < 4; ++f) bfin[f] = fgp[1152 + f * 64 + l];

    {
        const f16x8 pf0 = __builtin_bit_cast(f16x8, puA0);
        const f16x8 pf1 = __builtin_bit_cast(f16x8, puA1);
        const f16x8 a0 = pf0 * lfA0;
        const f16x8 a1 = pf1 * lfA1;
        f32x4 o = {0.f, 0.f, 0.f, 0.f};
        o = __builtin_amdgcn_mfma_f32_16x16x32_f16(bfin[0], pf0, o, 0, 0, 0);
        o = __builtin_amdgcn_mfma_f32_16x16x32_f16(bfin[1], pf1, o, 0, 0, 0);
        o = __builtin_amdgcn_mfma_f32_16x16x32_f16(bfin[2], a0, o, 0, 0, 0);
        o = __builtin_amdgcn_mfma_f32_16x16x32_f16(bfin[3], a1, o, 0, 0, 0);
        float s = o[0] + o[1] + o[2] + o[3];
        s += __shfl_xor(s, 16, 64);
        s += __shfl_xor(s, 32, 64);
        const float inv = 1.0f / fmaxf(s, 1e-10f);
        f32x4 res;
#pragma unroll
        for (int r = 0; r < 4; ++r) res[r] = o[r] * inv;
        *(f32x4*)(out + (rowbase + m) * 16 + 4 * q) = res;
    }
    {
        const f16x8 pf0 = __builtin_bit_cast(f16x8, puB0);
        const f16x8 pf1 = __builtin_bit_cast(f16x8, puB1);
        const f16x8 a0 = pf0 * lfB0;
        const f16x8 a1 = pf1 * lfB1;
        f32x4 o = {0.f, 0.f, 0.f, 0.f};
        o = __builtin_amdgcn_mfma_f32_16x16x32_f16(bfin[0], pf0, o, 0, 0, 0);
        o = __builtin_amdgcn_mfma_f32_16x16x32_f16(bfin[1], pf1, o, 0, 0, 0);
        o = __builtin_amdgcn_mfma_f32_16x16x32_f16(bfin[2], a0, o, 0, 0, 0);
        o = __builtin_amdgcn_mfma_f32_16x16x32_f16(bfin[3], a1, o, 0, 0, 0);
        float s = o[0] + o[1] + o[2] + o[3];
        s += __shfl_xor(s, 16, 64);
        s += __shfl_xor(s, 32, 64);
        const float inv = 1.0f / fmaxf(s, 1e-10f);
        f32x4 res;
#pragma unroll
        for (int r = 0; r < 4; ++r) res[r] = o[r] * inv;
        *(f32x4*)(out + (rowbase + 16 + m) * 16 + 4 * q) = res;
    }
}

extern "C" void kernel_launch(void* const* d_in, const int* in_sizes, int n_in,
                              void* d_out, int out_size, void* d_ws, size_t ws_size,
                              hipStream_t stream) {
    const float* x_pos = (const float*)d_in[0];
    const float* y_pos = (const float*)d_in[1];
    const float* sp    = (const float*)d_in[2];
    const float* sdl   = (const float*)d_in[3];
    const float* cls   = (const float*)d_in[4];
    const float* csl   = (const float*)d_in[5];
    const int*   mdp   = (const int*)d_in[6];

    // d_ws layout:
    //  [0,      22528) frags (11264 halves)
    //  [22528,  23040) tbl   (128 f32)
    //  [23040,  23552) row0  (128 f32)
    //  [23552,  56320) smg   (128x64 f32)
    //  [56320,  60416) csmg  (64x16 f32)
    //  [65536, 327680) H     (1024x64 f32)
    //  [327680,589824) V     (1024x64 f32)
    unsigned short* frags = (unsigned short*)d_ws;
    float* tbl  = (float*)((char*)d_ws + 22528);
    float* row0 = (float*)((char*)d_ws + 23040);
    float* smg  = (float*)((char*)d_ws + 23552);
    float* csmg = (float*)((char*)d_ws + 56320);
    float* H    = (float*)((char*)d_ws + 65536);
    float* V    = (float*)((char*)d_ws + 327680);

    fractal_setup_a<<<33, 256, 0, stream>>>(csl, cls, sp, sdl, smg, csmg, tbl);
    fractal_setup_b<<<557, 256, 0, stream>>>(smg, csmg, x_pos, y_pos, sp,
                                             frags, row0, H, V);

    const int B = in_sizes[0];  // 1048576 points; 128 points per block
    fractal_main<<<B / 128, 256, 0, stream>>>(x_pos, y_pos, mdp, frags, tbl, row0,
                                              csmg, H, V, (float*)d_out);
}